// Round 9
// baseline (238.537 us; speedup 1.0000x reference)
//
#include <hip/hip_runtime.h>
#include <hip/hip_bf16.h>
#include <stdint.h>

#define D_MODEL 1024
#define NH 16
#define DK 64
#define SEQ 2048
#define BATCH 2
#define NTOK (BATCH * SEQ)  // 4096

typedef __bf16 bf16;
typedef float f32x4 __attribute__((ext_vector_type(4)));
typedef __bf16 bf16x8 __attribute__((ext_vector_type(8)));
typedef __bf16 bf16x4 __attribute__((ext_vector_type(4)));

// 0.125 (1/sqrt(dk)) * log2(e): folded into Q so attn uses exp2 directly
#define QSCALE 0.18033687932432668f

__device__ __forceinline__ void gload_lds16(const void* g, void* l) {
  __builtin_amdgcn_global_load_lds(
      (const __attribute__((address_space(1))) void*)g,
      (__attribute__((address_space(3))) void*)l, 16, 0, 0);
}

// ---------------- fused prep kernel ----------------
__global__ void prep_kernel(const float* __restrict__ x, bf16* __restrict__ xb,
                            const float* __restrict__ wq, const float* __restrict__ wk,
                            const float* __restrict__ wv, const float* __restrict__ wo,
                            bf16* __restrict__ wt,
                            const int* __restrict__ mask, unsigned long long* __restrict__ bits) {
  __shared__ float tile[32][33];
  const int bx = blockIdx.x;
  const int tid = threadIdx.x;
  if (bx < 4096) {
    int i = bx * 256 + tid;
    float4 v = reinterpret_cast<const float4*>(x)[i];
    bf16x4 o;
    o[0] = (bf16)v.x; o[1] = (bf16)v.y; o[2] = (bf16)v.z; o[3] = (bf16)v.w;
    reinterpret_cast<bf16x4*>(xb)[i] = o;
  } else if (bx < 8192) {
    int blk = bx - 4096;
    const int jt = blk & 127;
    const int kt = blk >> 7;
    const int tx = tid & 31, ty = tid >> 5;
    const int j0 = jt * 32;
    const int sel = j0 >> 10;
    const float* w = (sel == 0) ? wq : (sel == 1) ? wk : (sel == 2) ? wv : wo;
    const int jj0 = j0 & 1023;
#pragma unroll
    for (int i = 0; i < 4; ++i)
      tile[ty + i * 8][tx] = w[(size_t)(kt * 32 + ty + i * 8) * 1024 + jj0 + tx];
    __syncthreads();
#pragma unroll
    for (int i = 0; i < 4; ++i)
      wt[(size_t)(j0 + ty + i * 8) * 1024 + kt * 32 + tx] = (bf16)tile[tx][ty + i * 8];
  } else {
    int gt = (bx - 8192) * 256 + tid;
    int wid = gt >> 6;
    int l = gt & 63;
    int m = mask[(size_t)wid * 64 + l];
    unsigned long long b = __ballot(m != 0);
    if (l == 0) bits[wid] = b;
  }
}

// ---------------- QKV GEMM: 128x128 tile, BK=64, XOR-swizzled LDS, XCD n-slice ----------------
__global__ __launch_bounds__(256) void gemm_qkv(
    const bf16* __restrict__ A, const bf16* __restrict__ Bt,
    const float* __restrict__ b0, const float* __restrict__ b1, const float* __restrict__ b2,
    bf16* __restrict__ out_q, bf16* __restrict__ out_k, bf16* __restrict__ out_vt) {
  __shared__ __align__(16) bf16 As[128 * 64];  // 16KB, rows 128B, XOR-swizzled chunks
  __shared__ __align__(16) bf16 Bs[128 * 64];  // 16KB
  const int tid = threadIdx.x;
  const int w = tid >> 6, l = tid & 63;
  const int wr = w >> 1, wc = w & 1;
  // XCD swizzle: 768 blocks = 96/XCD; each XCD owns 3 n-tiles x 32 m-tiles
  int lin = blockIdx.x + 24 * blockIdx.y;
  int xcd = lin & 7, idx = lin >> 3;
  const int n0 = (xcd * 3 + idx % 3) * 128;
  const int m0 = (idx / 3) * 128;
  f32x4 acc[4][4] = {};
  // staging: lane covers row w*8+(l>>3) within each 32-row group, chunk l&7 (pre-swizzled src)
  const int srow = w * 8 + (l >> 3);
  const int ssw = ((l & 7) ^ (l >> 3)) * 8;  // source chunk in elements
  char* AsB = (char*)As;
  char* BsB = (char*)Bs;

  for (int k0 = 0; k0 < 1024; k0 += 64) {
#pragma unroll
    for (int i = 0; i < 4; ++i) {
      gload_lds16(A + (size_t)(m0 + i * 32 + srow) * 1024 + k0 + ssw, AsB + i * 4096 + w * 1024);
      gload_lds16(Bt + (size_t)(n0 + i * 32 + srow) * 1024 + k0 + ssw, BsB + i * 4096 + w * 1024);
    }
    __syncthreads();
#pragma unroll
    for (int kk = 0; kk < 2; ++kk) {
      const int cc = (((kk * 4 + (l >> 4)) ^ (l & 7)) << 3);  // swizzled read chunk (rr&7 == l&7)
      bf16x8 af[4], bfr[4];
#pragma unroll
      for (int m = 0; m < 4; ++m)
        af[m] = *reinterpret_cast<const bf16x8*>(As + (wr * 64 + m * 16 + (l & 15)) * 64 + cc);
#pragma unroll
      for (int n = 0; n < 4; ++n)
        bfr[n] = *reinterpret_cast<const bf16x8*>(Bs + (wc * 64 + n * 16 + (l & 15)) * 64 + cc);
#pragma unroll
      for (int m = 0; m < 4; ++m)
#pragma unroll
        for (int n = 0; n < 4; ++n)
          acc[m][n] = __builtin_amdgcn_mfma_f32_16x16x32_bf16(af[m], bfr[n], acc[m][n], 0, 0, 0);
    }
    __syncthreads();
  }

#pragma unroll
  for (int m = 0; m < 4; ++m) {
    int ib = m0 + wr * 64 + m * 16 + 4 * (l >> 4);
#pragma unroll
    for (int n = 0; n < 4; ++n) {
      int j = n0 + wc * 64 + n * 16 + (l & 15);
      int sel = j >> 10, jj = j & 1023;
      const float* bp = (sel == 0) ? b0 : (sel == 1) ? b1 : b2;
      float bias = bp[jj];
      if (sel == 0) {
#pragma unroll
        for (int r = 0; r < 4; ++r)
          out_q[(size_t)(ib + r) * 1024 + jj] = (bf16)((acc[m][n][r] + bias) * QSCALE);
      } else if (sel == 1) {
#pragma unroll
        for (int r = 0; r < 4; ++r)
          out_k[(size_t)(ib + r) * 1024 + jj] = (bf16)(acc[m][n][r] + bias);
      } else {
        int hh = jj >> 6, dd = jj & 63;
        int bb = ib >> 11, ss = ib & 2047;
        bf16x4 v;
#pragma unroll
        for (int r = 0; r < 4; ++r) v[r] = (bf16)(acc[m][n][r] + bias);
        *reinterpret_cast<bf16x4*>(out_vt + ((size_t)(bb * NH + hh) * DK + dd) * SEQ + ss) = v;
      }
    }
  }
}

// ---------------- out-proj GEMM: 128x64 tile, BK=64, swizzled LDS, XCD n-slice ----------------
__global__ __launch_bounds__(256) void gemm_out(
    const bf16* __restrict__ A, const bf16* __restrict__ Bt,
    const float* __restrict__ bias, float* __restrict__ out) {
  __shared__ __align__(16) bf16 As[128 * 64];  // 16KB
  __shared__ __align__(16) bf16 Bs[64 * 64];   // 8KB
  const int tid = threadIdx.x;
  const int w = tid >> 6, l = tid & 63;
  const int wr = w >> 1, wc = w & 1;  // wave owns 64m x 32n
  // XCD swizzle: 512 blocks = 64/XCD; each XCD owns 2 n-tiles x 32 m-tiles
  int lin = blockIdx.x + 16 * blockIdx.y;
  int xcd = lin & 7, idx = lin >> 3;
  const int n0 = (xcd * 2 + idx % 2) * 64;
  const int m0 = (idx / 2) * 128;
  f32x4 acc[4][2] = {};
  const int srow = w * 8 + (l >> 3);
  const int ssw = ((l & 7) ^ (l >> 3)) * 8;
  char* AsB = (char*)As;
  char* BsB = (char*)Bs;

  for (int k0 = 0; k0 < 1024; k0 += 64) {
#pragma unroll
    for (int i = 0; i < 4; ++i)
      gload_lds16(A + (size_t)(m0 + i * 32 + srow) * 1024 + k0 + ssw, AsB + i * 4096 + w * 1024);
#pragma unroll
    for (int i = 0; i < 2; ++i)
      gload_lds16(Bt + (size_t)(n0 + i * 32 + srow) * 1024 + k0 + ssw, BsB + i * 4096 + w * 1024);
    __syncthreads();
#pragma unroll
    for (int kk = 0; kk < 2; ++kk) {
      const int cc = (((kk * 4 + (l >> 4)) ^ (l & 7)) << 3);
      bf16x8 af[4], bfr[2];
#pragma unroll
      for (int m = 0; m < 4; ++m)
        af[m] = *reinterpret_cast<const bf16x8*>(As + (wr * 64 + m * 16 + (l & 15)) * 64 + cc);
#pragma unroll
      for (int n = 0; n < 2; ++n)
        bfr[n] = *reinterpret_cast<const bf16x8*>(Bs + (wc * 32 + n * 16 + (l & 15)) * 64 + cc);
#pragma unroll
      for (int m = 0; m < 4; ++m)
#pragma unroll
        for (int n = 0; n < 2; ++n)
          acc[m][n] = __builtin_amdgcn_mfma_f32_16x16x32_bf16(af[m], bfr[n], acc[m][n], 0, 0, 0);
    }
    __syncthreads();
  }

#pragma unroll
  for (int m = 0; m < 4; ++m) {
    int ib = m0 + wr * 64 + m * 16 + 4 * (l >> 4);
#pragma unroll
    for (int n = 0; n < 2; ++n) {
      int j = n0 + wc * 32 + n * 16 + (l & 15);
      float bv = bias[j];
#pragma unroll
      for (int r = 0; r < 4; ++r)
        out[(size_t)(ib + r) * 1024 + j] = acc[m][n][r] + bv;
    }
  }
}

// ---------------- flash attention (swapped QK^T, in-lane softmax rows) ----------------
// grid 1024 blocks (XCD-swizzled), block 256 = 4 waves x 16 q-rows.
// lane(a=l>>4, c=l&15) holds P[key=16n+4a+r][q=c]; b64 P-writes; per-lane scalar lsum.
__global__ __launch_bounds__(256, 4) void attn_kernel(
    const bf16* __restrict__ qb, const bf16* __restrict__ kb,
    const bf16* __restrict__ vt, const unsigned long long* __restrict__ mbits,
    bf16* __restrict__ ob) {
  __shared__ __align__(16) bf16 Kbuf[2][64 * 64];  // [key][d] swizzled, 16KB
  __shared__ __align__(16) bf16 Vbuf[2][64 * 64];  // [d][key] swizzled, 16KB
  __shared__ __align__(16) bf16 Ps[4][16 * 64];    // per-wave [q][key] swizzled, 8KB
  const int tid = threadIdx.x;
  const int w = tid >> 6, l = tid & 63;
  int lin = blockIdx.x + 32 * blockIdx.y + 512 * blockIdx.z;
  int nl = (lin & 7) * 128 + (lin >> 3);
  const int qt = nl & 31, h = (nl >> 5) & 15, b = nl >> 9;
  const int q0 = qt * 64;
  const int qrow = q0 + w * 16;
  const int tok0 = b * SEQ + qrow;
  const int a = l >> 4, c = l & 15;

  bf16x8 qf[2];
#pragma unroll
  for (int kk = 0; kk < 2; ++kk)
    qf[kk] = *reinterpret_cast<const bf16x8*>(
        qb + (size_t)(tok0 + c) * 1024 + h * 64 + kk * 32 + a * 8);

  float lsum = 0.f;
  f32x4 oacc[4] = {};

  const int swz = ((l & 7) ^ (l >> 3)) * 8;
  const bf16* ksrc = kb + (size_t)(b * SEQ) * 1024 + h * 64;
  const bf16* vsrc = vt + (size_t)(b * NH + h) * DK * SEQ;
  const unsigned long long* mrow = mbits + ((size_t)(b * SEQ + qrow + c) << 5);

  auto STAGE = [&](int buf, int kt) {
    char* KsB = (char*)Kbuf[buf];
    char* VsB = (char*)Vbuf[buf];
#pragma unroll
    for (int i = 0; i < 2; ++i) {
      int row = i * 32 + w * 8 + (l >> 3);
      gload_lds16(ksrc + (size_t)(kt * 64 + row) * 1024 + swz, KsB + i * 4096 + w * 1024);
      gload_lds16(vsrc + (size_t)row * SEQ + kt * 64 + swz, VsB + i * 4096 + w * 1024);
    }
  };

  STAGE(0, 0);
  for (int kt = 0; kt < 32; ++kt) {
    const int cur = kt & 1;
    unsigned long long mw = mrow[kt];
    __builtin_amdgcn_sched_barrier(0);
    if (kt < 31) {
      STAGE(cur ^ 1, kt + 1);
      __builtin_amdgcn_sched_barrier(0);
      // queue: STAGE(kt)[4] mw[1] STAGE(kt+1)[4]; vmcnt(5) -> STAGE(kt) complete
      asm volatile("s_waitcnt vmcnt(5)" ::: "memory");
    } else {
      __builtin_amdgcn_sched_barrier(0);
      asm volatile("s_waitcnt vmcnt(0)" ::: "memory");
    }
    __builtin_amdgcn_s_barrier();
    __builtin_amdgcn_sched_barrier(0);

    const bf16* Ks = Kbuf[cur];
    const bf16* Vs = Vbuf[cur];

    // S^T = K Q^T : sa[n][r] = P[key=16n+4a+r][q=qrow+c]
    f32x4 sa[4] = {};
#pragma unroll
    for (int kk = 0; kk < 2; ++kk) {
      bf16x8 kf[4];
      int cc = kk * 4 + a;
#pragma unroll
      for (int n = 0; n < 4; ++n) {
        int rr = n * 16 + c;
        kf[n] = *reinterpret_cast<const bf16x8*>(Ks + rr * 64 + ((cc ^ (rr & 7)) << 3));
      }
#pragma unroll
      for (int n = 0; n < 4; ++n)
        sa[n] = __builtin_amdgcn_mfma_f32_16x16x32_bf16(kf[n], qf[kk], sa[n], 0, 0, 0);
    }

    // masked no-max softmax, per-lane scalar partial sum
    unsigned long long base = mw >> (a * 4);
    float ps[4][4];
#pragma unroll
    for (int n = 0; n < 4; ++n)
#pragma unroll
      for (int r = 0; r < 4; ++r) {
        bool on = (base >> (16 * n + r)) & 1ull;
        float p = on ? __builtin_amdgcn_exp2f(sa[n][r]) : 0.f;
        ps[n][r] = p;
        lsum += p;
      }
    // b64 P-writes: keys 16n+4a..+3 are contiguous in the swizzled row
#pragma unroll
    for (int n = 0; n < 4; ++n) {
      int chunk = (2 * n + (a >> 1)) ^ (c & 7);
      bf16x4 v4;
      v4[0] = (bf16)ps[n][0]; v4[1] = (bf16)ps[n][1];
      v4[2] = (bf16)ps[n][2]; v4[3] = (bf16)ps[n][3];
      *reinterpret_cast<bf16x4*>(Ps[w] + c * 64 + chunk * 8 + 4 * (a & 1)) = v4;
    }

    // O += P * V
#pragma unroll
    for (int kk = 0; kk < 2; ++kk) {
      bf16x8 pa = *reinterpret_cast<const bf16x8*>(Ps[w] + c * 64 + (((a + 4 * kk) ^ (c & 7)) << 3));
      bf16x8 vf[4];
#pragma unroll
      for (int dn = 0; dn < 4; ++dn) {
        int rr = dn * 16 + c;
        vf[dn] = *reinterpret_cast<const bf16x8*>(Vs + rr * 64 + (((kk * 4 + a) ^ (rr & 7)) << 3));
      }
#pragma unroll
      for (int dn = 0; dn < 4; ++dn)
        oacc[dn] = __builtin_amdgcn_mfma_f32_16x16x32_bf16(pa, vf[dn], oacc[dn], 0, 0, 0);
    }
    __builtin_amdgcn_sched_barrier(0);
    __builtin_amdgcn_s_barrier();
  }

  // epilogue: reduce lsum across a-groups, redistribute, store
  float s = lsum;
  s += __shfl_xor(s, 16);
  s += __shfl_xor(s, 32);
#pragma unroll
  for (int r = 0; r < 4; ++r) {
    float sr = __shfl(s, 4 * a + r);
    float inv = 1.f / fmaxf(sr, 1e-35f);
    int tok = tok0 + 4 * a + r;
#pragma unroll
    for (int dn = 0; dn < 4; ++dn)
      ob[(size_t)tok * 1024 + h * 64 + dn * 16 + c] = (bf16)(oacc[dn][r] * inv);
  }
}

// ---------------- launch ----------------
extern "C" void kernel_launch(void* const* d_in, const int* in_sizes, int n_in,
                              void* d_out, int out_size, void* d_ws, size_t ws_size,
                              hipStream_t stream) {
  const float* x = (const float*)d_in[0];
  const int* mask = (const int*)d_in[1];
  const float* wq = (const float*)d_in[2];
  const float* bq = (const float*)d_in[3];
  const float* wk = (const float*)d_in[4];
  const float* bk = (const float*)d_in[5];
  const float* wv = (const float*)d_in[6];
  const float* bv = (const float*)d_in[7];
  const float* wo = (const float*)d_in[8];
  const float* bo = (const float*)d_in[9];
  float* out = (float*)d_out;

  char* ws = (char*)d_ws;
  bf16* xb = (bf16*)(ws + (size_t)0);
  bf16* wt = (bf16*)(ws + ((size_t)8 << 20));
  bf16* qb = (bf16*)(ws + ((size_t)16 << 20));
  bf16* kb = (bf16*)(ws + ((size_t)24 << 20));
  bf16* vtb = (bf16*)(ws + ((size_t)32 << 20));
  bf16* ob = (bf16*)(ws + ((size_t)40 << 20));
  unsigned long long* mbits = (unsigned long long*)(ws + ((size_t)48 << 20));

  prep_kernel<<<40960, 256, 0, stream>>>(x, xb, wq, wk, wv, wo, wt, mask, mbits);
  gemm_qkv<<<dim3(24, 32), 256, 0, stream>>>(xb, wt, bq, bk, bv, qb, kb, vtb);
  attn_kernel<<<dim3(32, NH, BATCH), 256, 0, stream>>>(qb, kb, vtb, mbits, ob);
  gemm_out<<<dim3(16, 32), 256, 0, stream>>>(ob, wt + (size_t)3072 * 1024, bo, out);
}

// Round 10
// 233.241 us; speedup vs baseline: 1.0227x; 1.0227x over previous
//
#include <hip/hip_runtime.h>
#include <hip/hip_bf16.h>
#include <stdint.h>

#define D_MODEL 1024
#define NH 16
#define DK 64
#define SEQ 2048
#define BATCH 2
#define NTOK (BATCH * SEQ)  // 4096

typedef __bf16 bf16;
typedef float f32x4 __attribute__((ext_vector_type(4)));
typedef __bf16 bf16x8 __attribute__((ext_vector_type(8)));
typedef __bf16 bf16x4 __attribute__((ext_vector_type(4)));

// 0.125 (1/sqrt(dk)) * log2(e): folded into Q so attn uses exp2 directly
#define QSCALE 0.18033687932432668f

__device__ __forceinline__ void gload_lds16(const void* g, void* l) {
  __builtin_amdgcn_global_load_lds(
      (const __attribute__((address_space(1))) void*)g,
      (__attribute__((address_space(3))) void*)l, 16, 0, 0);
}

// ---------------- fused prep kernel ----------------
__global__ void prep_kernel(const float* __restrict__ x, bf16* __restrict__ xb,
                            const float* __restrict__ wq, const float* __restrict__ wk,
                            const float* __restrict__ wv, const float* __restrict__ wo,
                            bf16* __restrict__ wt,
                            const int* __restrict__ mask, unsigned long long* __restrict__ bits) {
  __shared__ float tile[32][33];
  const int bx = blockIdx.x;
  const int tid = threadIdx.x;
  if (bx < 4096) {
    int i = bx * 256 + tid;
    float4 v = reinterpret_cast<const float4*>(x)[i];
    bf16x4 o;
    o[0] = (bf16)v.x; o[1] = (bf16)v.y; o[2] = (bf16)v.z; o[3] = (bf16)v.w;
    reinterpret_cast<bf16x4*>(xb)[i] = o;
  } else if (bx < 8192) {
    int blk = bx - 4096;
    const int jt = blk & 127;
    const int kt = blk >> 7;
    const int tx = tid & 31, ty = tid >> 5;
    const int j0 = jt * 32;
    const int sel = j0 >> 10;
    const float* w = (sel == 0) ? wq : (sel == 1) ? wk : (sel == 2) ? wv : wo;
    const int jj0 = j0 & 1023;
#pragma unroll
    for (int i = 0; i < 4; ++i)
      tile[ty + i * 8][tx] = w[(size_t)(kt * 32 + ty + i * 8) * 1024 + jj0 + tx];
    __syncthreads();
#pragma unroll
    for (int i = 0; i < 4; ++i)
      wt[(size_t)(j0 + ty + i * 8) * 1024 + kt * 32 + tx] = (bf16)tile[tx][ty + i * 8];
  } else {
    int gt = (bx - 8192) * 256 + tid;
    int wid = gt >> 6;
    int l = gt & 63;
    int m = mask[(size_t)wid * 64 + l];
    unsigned long long b = __ballot(m != 0);
    if (l == 0) bits[wid] = b;
  }
}

// ---------------- QKV GEMM: 128x128 tile, BK=32, plain 2-barrier (m97 structure), XCD n-slice ----------------
__global__ __launch_bounds__(256) void gemm_qkv(
    const bf16* __restrict__ A, const bf16* __restrict__ Bt,
    const float* __restrict__ b0, const float* __restrict__ b1, const float* __restrict__ b2,
    bf16* __restrict__ out_q, bf16* __restrict__ out_k, bf16* __restrict__ out_vt) {
  __shared__ __align__(16) bf16 As[128 * 32];
  __shared__ __align__(16) bf16 Bs[128 * 32];
  const int tid = threadIdx.x;
  const int w = tid >> 6, l = tid & 63;
  const int wr = w >> 1, wc = w & 1;
  // XCD slice: 768 blocks = 96/XCD; each XCD owns 3 n-tiles x 32 m-tiles
  int lin = blockIdx.x + 24 * blockIdx.y;
  int xcd = lin & 7, idx = lin >> 3;
  const int n0 = (xcd * 3 + idx % 3) * 128;
  const int m0 = (idx / 3) * 128;
  f32x4 acc[4][4] = {};
  const int lrow = l >> 2;
  const int lc8 = (l & 3) * 8;
  char* AsB = (char*)As;
  char* BsB = (char*)Bs;

  for (int k0 = 0; k0 < 1024; k0 += 32) {
#pragma unroll
    for (int is = 0; is < 2; ++is) {
      int arow = m0 + is * 64 + w * 16 + lrow;
      gload_lds16(A + (size_t)arow * 1024 + k0 + lc8, AsB + is * 4096 + w * 1024);
      int brow = n0 + is * 64 + w * 16 + lrow;
      gload_lds16(Bt + (size_t)brow * 1024 + k0 + lc8, BsB + is * 4096 + w * 1024);
    }
    __syncthreads();
    bf16x8 af[4], bfr[4];
#pragma unroll
    for (int m = 0; m < 4; ++m)
      af[m] = *reinterpret_cast<const bf16x8*>(As + (wr * 64 + m * 16 + (l & 15)) * 32 + (l >> 4) * 8);
#pragma unroll
    for (int n = 0; n < 4; ++n)
      bfr[n] = *reinterpret_cast<const bf16x8*>(Bs + (wc * 64 + n * 16 + (l & 15)) * 32 + (l >> 4) * 8);
#pragma unroll
    for (int m = 0; m < 4; ++m)
#pragma unroll
      for (int n = 0; n < 4; ++n)
        acc[m][n] = __builtin_amdgcn_mfma_f32_16x16x32_bf16(af[m], bfr[n], acc[m][n], 0, 0, 0);
    __syncthreads();
  }

#pragma unroll
  for (int m = 0; m < 4; ++m) {
    int ib = m0 + wr * 64 + m * 16 + 4 * (l >> 4);
#pragma unroll
    for (int n = 0; n < 4; ++n) {
      int j = n0 + wc * 64 + n * 16 + (l & 15);
      int sel = j >> 10, jj = j & 1023;
      const float* bp = (sel == 0) ? b0 : (sel == 1) ? b1 : b2;
      float bias = bp[jj];
      if (sel == 0) {
#pragma unroll
        for (int r = 0; r < 4; ++r)
          out_q[(size_t)(ib + r) * 1024 + jj] = (bf16)((acc[m][n][r] + bias) * QSCALE);
      } else if (sel == 1) {
#pragma unroll
        for (int r = 0; r < 4; ++r)
          out_k[(size_t)(ib + r) * 1024 + jj] = (bf16)(acc[m][n][r] + bias);
      } else {
        int hh = jj >> 6, dd = jj & 63;
        int bb = ib >> 11, ss = ib & 2047;
        bf16x4 v;
#pragma unroll
        for (int r = 0; r < 4; ++r) v[r] = (bf16)(acc[m][n][r] + bias);
        *reinterpret_cast<bf16x4*>(out_vt + ((size_t)(bb * NH + hh) * DK + dd) * SEQ + ss) = v;
      }
    }
  }
}

// ---------------- out-proj GEMM: 128x64 tile, BK=32, plain 2-barrier, XCD n-slice ----------------
__global__ __launch_bounds__(256) void gemm_out(
    const bf16* __restrict__ A, const bf16* __restrict__ Bt,
    const float* __restrict__ bias, float* __restrict__ out) {
  __shared__ __align__(16) bf16 As[128 * 32];
  __shared__ __align__(16) bf16 Bs[64 * 32];
  const int tid = threadIdx.x;
  const int w = tid >> 6, l = tid & 63;
  const int wr = w >> 1, wc = w & 1;
  // XCD slice: 512 blocks = 64/XCD; each XCD owns 2 n-tiles x 32 m-tiles
  int lin = blockIdx.x + 16 * blockIdx.y;
  int xcd = lin & 7, idx = lin >> 3;
  const int n0 = (xcd * 2 + idx % 2) * 64;
  const int m0 = (idx / 2) * 128;
  f32x4 acc[4][2] = {};
  const int lrow = l >> 2;
  const int lc8 = (l & 3) * 8;
  char* AsB = (char*)As;
  char* BsB = (char*)Bs;

  for (int k0 = 0; k0 < 1024; k0 += 32) {
#pragma unroll
    for (int is = 0; is < 2; ++is) {
      int arow = m0 + is * 64 + w * 16 + lrow;
      gload_lds16(A + (size_t)arow * 1024 + k0 + lc8, AsB + is * 4096 + w * 1024);
    }
    gload_lds16(Bt + (size_t)(n0 + w * 16 + lrow) * 1024 + k0 + lc8, BsB + w * 1024);
    __syncthreads();
    bf16x8 af[4], bfr[2];
#pragma unroll
    for (int m = 0; m < 4; ++m)
      af[m] = *reinterpret_cast<const bf16x8*>(As + (wr * 64 + m * 16 + (l & 15)) * 32 + (l >> 4) * 8);
#pragma unroll
    for (int n = 0; n < 2; ++n)
      bfr[n] = *reinterpret_cast<const bf16x8*>(Bs + (wc * 32 + n * 16 + (l & 15)) * 32 + (l >> 4) * 8);
#pragma unroll
    for (int m = 0; m < 4; ++m)
#pragma unroll
      for (int n = 0; n < 2; ++n)
        acc[m][n] = __builtin_amdgcn_mfma_f32_16x16x32_bf16(af[m], bfr[n], acc[m][n], 0, 0, 0);
    __syncthreads();
  }

#pragma unroll
  for (int m = 0; m < 4; ++m) {
    int ib = m0 + wr * 64 + m * 16 + 4 * (l >> 4);
#pragma unroll
    for (int n = 0; n < 2; ++n) {
      int j = n0 + wc * 32 + n * 16 + (l & 15);
      float bv = bias[j];
#pragma unroll
      for (int r = 0; r < 4; ++r)
        out[(size_t)(ib + r) * 1024 + j] = acc[m][n][r] + bv;
    }
  }
}

// ---------------- flash attention: 8 waves/block, 128 q-rows/block ----------------
// grid 512 blocks (XCD-swizzled), 2 blocks/CU, LDS 48KB, 16 waves/CU.
// Waves 0-3 stage K (2 gload_lds each), waves 4-7 stage V: per-tile staging serves
// 128 q-rows (2x reuse vs 4-wave version). Swapped QK^T, no-max softmax, deferred sum.
__global__ __launch_bounds__(512, 4) void attn_kernel(
    const bf16* __restrict__ qb, const bf16* __restrict__ kb,
    const bf16* __restrict__ vt, const unsigned long long* __restrict__ mbits,
    bf16* __restrict__ ob) {
  __shared__ __align__(16) bf16 Kbuf[2][64 * 64];  // [key][d] swizzled, 16KB
  __shared__ __align__(16) bf16 Vbuf[2][64 * 64];  // [d][key] swizzled, 16KB
  __shared__ __align__(16) bf16 Ps[8][16 * 64];    // per-wave [q][key] swizzled, 16KB
  const int tid = threadIdx.x;
  const int w = tid >> 6, l = tid & 63;
  // XCD swizzle: 512 blocks, 64/XCD
  int lin = blockIdx.x + 16 * blockIdx.y + 256 * blockIdx.z;
  int nl = (lin & 7) * 64 + (lin >> 3);
  const int qt = nl & 15, h = (nl >> 4) & 15, b = nl >> 8;
  const int qrow = qt * 128 + w * 16;  // this wave's 16 q-rows
  const int tok0 = b * SEQ + qrow;
  const int a = l >> 4, c = l & 15;

  // Q fragments (pre-scaled by QSCALE); used as MFMA B-operand
  bf16x8 qf[2];
#pragma unroll
  for (int kk = 0; kk < 2; ++kk)
    qf[kk] = *reinterpret_cast<const bf16x8*>(
        qb + (size_t)(tok0 + c) * 1024 + h * 64 + kk * 32 + a * 8);

  float lsum = 0.f;
  f32x4 oacc[4] = {};

  const int swz = ((l & 7) ^ (l >> 3)) * 8;  // pre-swizzled source chunk
  const bf16* ksrc = kb + (size_t)(b * SEQ) * 1024 + h * 64;
  const bf16* vsrc = vt + (size_t)(b * NH + h) * DK * SEQ;
  const unsigned long long* mrow = mbits + ((size_t)(b * SEQ + qrow + c) << 5);

  // wave-split staging: w<4 stage K rows w*16..+15; w>=4 stage V rows (w-4)*16..+15
  auto STAGE = [&](int buf, int kt) {
    if (w < 4) {
      char* KsB = (char*)Kbuf[buf];
#pragma unroll
      for (int i = 0; i < 2; ++i) {
        int row = w * 16 + i * 8 + (l >> 3);
        gload_lds16(ksrc + (size_t)(kt * 64 + row) * 1024 + swz, KsB + w * 2048 + i * 1024);
      }
    } else {
      char* VsB = (char*)Vbuf[buf];
#pragma unroll
      for (int i = 0; i < 2; ++i) {
        int row = (w - 4) * 16 + i * 8 + (l >> 3);
        gload_lds16(vsrc + (size_t)row * SEQ + kt * 64 + swz, VsB + (w - 4) * 2048 + i * 1024);
      }
    }
  };

  STAGE(0, 0);
  for (int kt = 0; kt < 32; ++kt) {
    const int cur = kt & 1;
    unsigned long long mw = mrow[kt];
    __builtin_amdgcn_sched_barrier(0);
    if (kt < 31) {
      STAGE(cur ^ 1, kt + 1);
      __builtin_amdgcn_sched_barrier(0);
      // per-wave queue: STAGE(kt)[2] mw[1] STAGE(kt+1)[2] -> vmcnt(3) = STAGE(kt) done
      asm volatile("s_waitcnt vmcnt(3)" ::: "memory");
    } else {
      __builtin_amdgcn_sched_barrier(0);
      asm volatile("s_waitcnt vmcnt(1)" ::: "memory");  // STAGE(31) done; mw pending
    }
    __builtin_amdgcn_s_barrier();
    __builtin_amdgcn_sched_barrier(0);

    const bf16* Ks = Kbuf[cur];
    const bf16* Vs = Vbuf[cur];

    // S^T = K Q^T : sa[n][r] = P[key=16n+4a+r][q=qrow+c]
    f32x4 sa[4] = {};
#pragma unroll
    for (int kk = 0; kk < 2; ++kk) {
      bf16x8 kf[4];
      int cc = kk * 4 + a;
#pragma unroll
      for (int n = 0; n < 4; ++n) {
        int rr = n * 16 + c;
        kf[n] = *reinterpret_cast<const bf16x8*>(Ks + rr * 64 + ((cc ^ (rr & 7)) << 3));
      }
#pragma unroll
      for (int n = 0; n < 4; ++n)
        sa[n] = __builtin_amdgcn_mfma_f32_16x16x32_bf16(kf[n], qf[kk], sa[n], 0, 0, 0);
    }

    // masked no-max softmax, per-lane scalar partial sum
    unsigned long long base = mw >> (a * 4);
    float ps[4][4];
#pragma unroll
    for (int n = 0; n < 4; ++n)
#pragma unroll
      for (int r = 0; r < 4; ++r) {
        bool on = (base >> (16 * n + r)) & 1ull;
        float p = on ? __builtin_amdgcn_exp2f(sa[n][r]) : 0.f;
        ps[n][r] = p;
        lsum += p;
      }
    // b64 P-writes: keys 16n+4a..+3 contiguous in the swizzled row
#pragma unroll
    for (int n = 0; n < 4; ++n) {
      int chunk = (2 * n + (a >> 1)) ^ (c & 7);
      bf16x4 v4;
      v4[0] = (bf16)ps[n][0]; v4[1] = (bf16)ps[n][1];
      v4[2] = (bf16)ps[n][2]; v4[3] = (bf16)ps[n][3];
      *reinterpret_cast<bf16x4*>(Ps[w] + c * 64 + chunk * 8 + 4 * (a & 1)) = v4;
    }

    // O += P * V
#pragma unroll
    for (int kk = 0; kk < 2; ++kk) {
      bf16x8 pa = *reinterpret_cast<const bf16x8*>(Ps[w] + c * 64 + (((a + 4 * kk) ^ (c & 7)) << 3));
      bf16x8 vf[4];
#pragma unroll
      for (int dn = 0; dn < 4; ++dn) {
        int rr = dn * 16 + c;
        vf[dn] = *reinterpret_cast<const bf16x8*>(Vs + rr * 64 + (((kk * 4 + a) ^ (rr & 7)) << 3));
      }
#pragma unroll
      for (int dn = 0; dn < 4; ++dn)
        oacc[dn] = __builtin_amdgcn_mfma_f32_16x16x32_bf16(pa, vf[dn], oacc[dn], 0, 0, 0);
    }
    __builtin_amdgcn_sched_barrier(0);
    __builtin_amdgcn_s_barrier();
  }

  // epilogue: reduce lsum across a-groups, redistribute, store
  float s = lsum;
  s += __shfl_xor(s, 16);
  s += __shfl_xor(s, 32);
#pragma unroll
  for (int r = 0; r < 4; ++r) {
    float sr = __shfl(s, 4 * a + r);
    float inv = 1.f / fmaxf(sr, 1e-35f);
    int tok = tok0 + 4 * a + r;
#pragma unroll
    for (int dn = 0; dn < 4; ++dn)
      ob[(size_t)tok * 1024 + h * 64 + dn * 16 + c] = (bf16)(oacc[dn][r] * inv);
  }
}

// ---------------- launch ----------------
extern "C" void kernel_launch(void* const* d_in, const int* in_sizes, int n_in,
                              void* d_out, int out_size, void* d_ws, size_t ws_size,
                              hipStream_t stream) {
  const float* x = (const float*)d_in[0];
  const int* mask = (const int*)d_in[1];
  const float* wq = (const float*)d_in[2];
  const float* bq = (const float*)d_in[3];
  const float* wk = (const float*)d_in[4];
  const float* bk = (const float*)d_in[5];
  const float* wv = (const float*)d_in[6];
  const float* bv = (const float*)d_in[7];
  const float* wo = (const float*)d_in[8];
  const float* bo = (const float*)d_in[9];
  float* out = (float*)d_out;

  char* ws = (char*)d_ws;
  bf16* xb = (bf16*)(ws + (size_t)0);
  bf16* wt = (bf16*)(ws + ((size_t)8 << 20));
  bf16* qb = (bf16*)(ws + ((size_t)16 << 20));
  bf16* kb = (bf16*)(ws + ((size_t)24 << 20));
  bf16* vtb = (bf16*)(ws + ((size_t)32 << 20));
  bf16* ob = (bf16*)(ws + ((size_t)40 << 20));
  unsigned long long* mbits = (unsigned long long*)(ws + ((size_t)48 << 20));

  prep_kernel<<<40960, 256, 0, stream>>>(x, xb, wq, wk, wv, wo, wt, mask, mbits);
  gemm_qkv<<<dim3(24, 32), 256, 0, stream>>>(xb, wt, bq, bk, bv, qb, kb, vtb);
  attn_kernel<<<dim3(16, NH, BATCH), 512, 0, stream>>>(qb, kb, vtb, mbits, ob);
  gemm_out<<<dim3(16, 32), 256, 0, stream>>>(ob, wt + (size_t)3072 * 1024, bo, out);
}